// Round 11
// baseline (206.218 us; speedup 1.0000x reference)
//
#include <hip/hip_runtime.h>
#include <math.h>

#define N_NODES 20000
#define N_EDGES 50000
#define N_SLOTS 256   // N_PAIRS * 2 flattened targets
#define N_PAIRS 128
#define CAP 32        // max incident edges per slot (deg ~ Poisson(5); P(>=32)~1e-16)
#define MSTRIDE 16384 // floats per transposed-matrix slot in ws
#define NMAT 19
#define TFLAG (1 << 30)
#define HSZ 1024      // LDS hash table size (load factor 0.25)
#define NBLK 256
#define BATCH 16      // phase-B edge batch: one batch covers ~every slot

// ---------- helpers ----------
__device__ __forceinline__ float4 relu4(float4 v) {
    return make_float4(fmaxf(v.x, 0.f), fmaxf(v.y, 0.f), fmaxf(v.z, 0.f), fmaxf(v.w, 0.f));
}
__device__ __forceinline__ float4 add4(float4 a, float4 b) {
    return make_float4(a.x + b.x, a.y + b.y, a.z + b.z, a.w + b.w);
}
__device__ __forceinline__ void fma4(float4& acc, const float4 w, const float s) {
    acc.x = fmaf(w.x, s, acc.x); acc.y = fmaf(w.y, s, acc.y);
    acc.z = fmaf(w.z, s, acc.z); acc.w = fmaf(w.w, s, acc.w);
}
#define F4Z make_float4(0.f, 0.f, 0.f, 0.f)
__device__ __forceinline__ float4 shfl4(float4 v, int src) {
    return make_float4(__shfl(v.x, src, 32), __shfl(v.y, src, 32),
                       __shfl(v.z, src, 32), __shfl(v.w, src, 32));
}
__device__ __forceinline__ float4 xorsum4(float4 v, int m) {
    return make_float4(v.x + __shfl_xor(v.x, m), v.y + __shfl_xor(v.y, m),
                       v.z + __shfl_xor(v.z, m), v.w + __shfl_xor(v.w, m));
}

// manual grid barrier (r4: coherence-point poll; r6: split release/acquire
// fences). r7/r8: 512-thread blocks cap VGPR at 128 -> spills; stay at 256.
// r10: weight preload defeats compiler pipelining -> keep r9 matvec form.
__device__ __forceinline__ void gbar(unsigned* cnt, unsigned target, bool wait) {
    __syncthreads();
    if (threadIdx.x == 0) {
        __builtin_amdgcn_fence(__ATOMIC_RELEASE, "agent");  // wbl2, no inv
        __hip_atomic_fetch_add(cnt, 1u, __ATOMIC_RELAXED, __HIP_MEMORY_SCOPE_AGENT);
        if (wait) {
            int it = 0;
            while (true) {
                unsigned v;
                if ((it++ & 7) != 7)
                    v = __hip_atomic_load(cnt, __ATOMIC_RELAXED,
                                          __HIP_MEMORY_SCOPE_SYSTEM);
                else
                    v = __hip_atomic_fetch_add(cnt, 0u, __ATOMIC_RELAXED,
                                               __HIP_MEMORY_SCOPE_AGENT);
                if (v >= target) break;
                __builtin_amdgcn_s_sleep(16);
            }
            __builtin_amdgcn_fence(__ATOMIC_ACQUIRE, "agent");  // single inv
        }
    }
    __syncthreads();
}

// ===== r11 register-chained 1-item matvecs (phase A / epilogue) =====
// mv_reg_g8: group g computes partials for all 128 outputs using ITS 16-element
// x-chunk held in registers (xv[0..3] = elements (g*16)..(g*16+15)).
__device__ __forceinline__ float4 mv_reg_g8(const float* __restrict__ WT,
                                            const float4 xv[4], int g, int jj) {
    const float4* W4 = (const float4*)WT;
    float4 acc = F4Z;
#pragma unroll
    for (int kk4 = 0; kk4 < 4; ++kk4) {
        int k4 = g * 4 + kk4;
        float4 x = xv[kk4];
        fma4(acc, W4[(k4 * 4 + 0) * 32 + jj], x.x);
        fma4(acc, W4[(k4 * 4 + 1) * 32 + jj], x.y);
        fma4(acc, W4[(k4 * 4 + 2) * 32 + jj], x.z);
        fma4(acc, W4[(k4 * 4 + 3) * 32 + jj], x.w);
    }
    return acc;
}
__device__ __forceinline__ float4 mv_reg_g8_64(const float* __restrict__ WT,
                                               const float4 xv[4], int g, int jj) {
    const float4* W4 = (const float4*)WT;
    int j16 = jj & 15;
    float4 acc = F4Z;
#pragma unroll
    for (int kk4 = 0; kk4 < 4; ++kk4) {
        int k4 = g * 4 + kk4;
        float4 x = xv[kk4];
        fma4(acc, W4[(k4 * 4 + 0) * 16 + j16], x.x);
        fma4(acc, W4[(k4 * 4 + 1) * 16 + j16], x.y);
        fma4(acc, W4[(k4 * 4 + 2) * 16 + j16], x.z);
        fma4(acc, W4[(k4 * 4 + 3) * 16 + j16], x.w);
    }
    return acc;
}
// comb_wave: after ONE barrier, each 32-thread group sums the 8 pb partials of
// ITS 4 output columns (parallel across all groups — replaces the g==0-only
// serial comb), adds bias, and broadcasts so all lanes hold xv[0..3] for the
// NEXT matvec directly in registers. pb must be double-buffered by caller.
__device__ __forceinline__ void comb_wave(const float4* pbuf, int g, int jj,
                                          const float* __restrict__ bias,
                                          float4 xv[4]) {
    int col = jj >> 3, gp = jj & 7;
    float4 v = pbuf[gp * 32 + g * 4 + col];
    v = xorsum4(v, 1); v = xorsum4(v, 2); v = xorsum4(v, 4);
    v = add4(v, *(const float4*)(bias + (g * 4 + col) * 4));
#pragma unroll
    for (int cc = 0; cc < 4; ++cc) xv[cc] = shfl4(v, cc * 8);
}
// designated lanes store the group's chunk to an LDS vector (for later phases)
__device__ __forceinline__ void store_chunk(float* dst, int g, int jj,
                                            const float4 xv[4]) {
    if ((jj & 7) == 0) *(float4*)(dst + (g * 4 + (jj >> 3)) * 4) = xv[jj >> 3];
}
__device__ __forceinline__ float4 comb1_g8(const float4* pb, int jj) {
    float4 s = pb[jj];
#pragma unroll
    for (int gp = 1; gp < 8; ++gp) s = add4(s, pb[gp * 32 + jj]);
    return s;
}

// ===== 16-item, 8-group matvec (r9 form — compiler pipelines loads) =====
__device__ __forceinline__ void mv16_g8(const float* __restrict__ WT,
                                        const float* __restrict__ xs,
                                        int g, int jj, float4* acc) {
    const float4* W4 = (const float4*)WT;
    const float4* x4 = (const float4*)xs;
#pragma unroll
    for (int kk4 = 0; kk4 < 4; ++kk4) {
        int k4 = g * 4 + kk4;
        float4 w0 = W4[(k4 * 4 + 0) * 32 + jj];
        float4 w1 = W4[(k4 * 4 + 1) * 32 + jj];
        float4 w2 = W4[(k4 * 4 + 2) * 32 + jj];
        float4 w3 = W4[(k4 * 4 + 3) * 32 + jj];
#pragma unroll
        for (int e = 0; e < 16; ++e) {
            float4 xv = x4[e * 32 + k4];
            fma4(acc[e], w0, xv.x); fma4(acc[e], w1, xv.y);
            fma4(acc[e], w2, xv.z); fma4(acc[e], w3, xv.w);
        }
    }
}
__device__ __forceinline__ float4 comb16_g8(const float4* pb, int it, int jj) {
    float4 s = pb[it * 32 + jj];
#pragma unroll
    for (int gp = 1; gp < 8; ++gp) s = add4(s, pb[(gp * 16 + it) * 32 + jj]);
    return s;
}

// ===== 4-group variants for the 128-thread pair head =====
__device__ __forceinline__ float4 mv_ks1(const float* __restrict__ WT,
                                         const float* __restrict__ xv128,
                                         int g, int jj) {
    const float4* W4 = (const float4*)WT;
    const float4* x4 = (const float4*)xv128;
    float4 acc = F4Z;
#pragma unroll 2
    for (int kk4 = 0; kk4 < 8; ++kk4) {
        int k4 = g * 8 + kk4;
        float4 xv = x4[k4];
        fma4(acc, W4[(k4 * 4 + 0) * 32 + jj], xv.x);
        fma4(acc, W4[(k4 * 4 + 1) * 32 + jj], xv.y);
        fma4(acc, W4[(k4 * 4 + 2) * 32 + jj], xv.z);
        fma4(acc, W4[(k4 * 4 + 3) * 32 + jj], xv.w);
    }
    return acc;
}
__device__ __forceinline__ float4 mv_ks1_64(const float* __restrict__ WT,
                                            const float* __restrict__ xv128,
                                            int g, int jj) {
    const float4* W4 = (const float4*)WT;
    const float4* x4 = (const float4*)xv128;
    int j16 = jj & 15;
    float4 acc = F4Z;
#pragma unroll 2
    for (int kk4 = 0; kk4 < 8; ++kk4) {
        int k4 = g * 8 + kk4;
        float4 xv = x4[k4];
        fma4(acc, W4[(k4 * 4 + 0) * 16 + j16], xv.x);
        fma4(acc, W4[(k4 * 4 + 1) * 16 + j16], xv.y);
        fma4(acc, W4[(k4 * 4 + 2) * 16 + j16], xv.z);
        fma4(acc, W4[(k4 * 4 + 3) * 16 + j16], xv.w);
    }
    return acc;
}
__device__ __forceinline__ float4 comb1(const float4* pb, int jj) {
    return add4(add4(pb[jj], pb[32 + jj]), add4(pb[64 + jj], pb[96 + jj]));
}

// ---------- hash helpers ----------
__device__ __forceinline__ unsigned thash(int key) {
    return ((unsigned)key * 2654435761u) >> 22;
}
__device__ __forceinline__ bool hexists(const int* __restrict__ hkey, int key) {
    unsigned h = thash(key);
    while (true) {
        int k = hkey[h];
        if (k == -1) return false;
        if (k == key) return true;
        h = (h + 1) & (HSZ - 1);
    }
}
__device__ __forceinline__ void hemit_g(const int* __restrict__ hkey,
                                        const int* __restrict__ hval,
                                        int* __restrict__ gcnt,
                                        int2* __restrict__ lst,
                                        int key, int e, int nbrf) {
    unsigned h = thash(key);
    while (true) {
        int k = hkey[h];
        if (k == -1) return;
        if (k == key) {
            int s = hval[h];
            int pos = atomicAdd(&gcnt[s], 1);
            if (pos < CAP) lst[s * CAP + pos] = make_int2(e, nbrf);
        }
        h = (h + 1) & (HSZ - 1);
    }
}

// ---------- params ----------
struct Params {
    const float* nf; const int* ei; const float* ts; const int* tp;
    const float* inW; const float* inb;
    const float* teW1; const float* teb1; const float* teW2; const float* teb2;
    const float* aiW; const float* aib; const float* aoW; const float* aob;
    const float* ftW; const float* ftb; const float* opW; const float* opb;
    const float* o1W; const float* o1b; const float* o2W; const float* o2b;
    const float* l1W; const float* l1b; const float* l2W; const float* l2b;
    const float* l3W; const float* l3b;
    float* out; float* x; int* cnt; int2* lst; float* emb; float* WT;
    unsigned* bar;
};

// single kernel, 256 threads (r9 base). r11: phase-A/epilogue matvec chains
// are register-fed: one barrier per stage, parallel per-group combine via
// shuffles, pb double-buffered (pbA/pbB 4KB slices inside pb).
__global__ __launch_bounds__(256, 1) void k_fused(Params P) {
    __shared__ __align__(16) float xu[128], tfv[128], qv[128], sv[128];
    __shared__ __align__(16) float xs[BATCH * 128], t1s[BATCH * 128];
    __shared__ __align__(16) float x0s[BATCH * 128], zs[BATCH * 128];
    __shared__ __align__(16) float4 pb[8 * 16 * 32];  // 64 KB partials
    __shared__ __align__(16) float vbl[CAP * 128];    // 16 KB values
    __shared__ float scl[CAP * 4];
    __shared__ int nbr_s[BATCH], tf_s[BATCH];
    __shared__ float ts_s[BATCH];
    __shared__ __align__(16) float tile[32][129];     // prep: transpose staging
    __shared__ int hkey[HSZ], hval[HSZ];              // prep: target hash

    const int b = blockIdx.x, tid = threadIdx.x, g = tid >> 5, jj = tid & 31;
    float4* pbA = pb;            // double-buffered 1-item matvec partials
    float4* pbB = pb + 32 * 32;

    // ================= prep phase =================
    if (b < 72) {  // weight transposes
        int m, r0, rows;
        if (b < 68) { m = b >> 2; r0 = (b & 3) * 32; rows = 128; }
        else { int mm = b - 68; m = 17 + (mm >> 1); r0 = (mm & 1) * 32; rows = 64; }
        const float* src;
        if (m == 0) src = P.inW;
        else if (m <= 2) src = P.ftW + (m - 1) * MSTRIDE;
        else if (m <= 4) src = P.teW2 + (m - 3) * MSTRIDE;
        else if (m <= 10) src = P.aiW + (m - 5) * MSTRIDE;  // q0,k0,v0,q1,k1,v1
        else if (m <= 12) src = P.aoW + (m - 11) * MSTRIDE;
        else if (m <= 14) src = P.opW + (m - 13) * MSTRIDE;
        else if (m == 15) src = P.o1W;
        else if (m == 16) src = P.l1W;
        else if (m == 17) src = P.o2W;
        else src = P.l2W;
        float* dst = P.WT + m * MSTRIDE;
        for (int idx = tid; idx < 32 * 128; idx += 256) {
            int r = idx >> 7, cc = idx & 127;
            tile[r][cc] = src[(r0 + r) * 128 + cc];
        }
        __syncthreads();
        for (int idx = tid; idx < 128 * 32; idx += 256) {
            int k = idx >> 5, jr = idx & 31;
            dst[k * rows + r0 + jr] = tile[jr][k];
        }
    } else {
        // blocks 72..255: distributed O(E) hash scan, global-atomic emits.
        for (int i = tid; i < HSZ; i += 256) hkey[i] = -1;
        __syncthreads();
        {   // insert all 256 (target, slot) pairs, duplicates get own cells
            int uu = P.tp[tid];
            unsigned h = thash(uu);
            while (atomicCAS(&hkey[h], -1, uu) != -1) h = (h + 1) & (HSZ - 1);
            hval[h] = tid;
        }
        __syncthreads();
        const int4* s4 = (const int4*)P.ei;
        const int4* d4 = (const int4*)(P.ei + N_EDGES);
        const int NE4 = N_EDGES / 4;                     // 12500
        const int nscan = NBLK - 72;                     // 184 scan blocks
        const int chunk = (NE4 + nscan - 1) / nscan;     // 68
        const int start = (b - 72) * chunk;
        const int end = min(start + chunk, NE4);
        for (int e4 = start + tid; e4 < end; e4 += 256) {
            int4 s = s4[e4];
            int4 d = d4[e4];
            int ss[4] = {s.x, s.y, s.z, s.w};
            int dd[4] = {d.x, d.y, d.z, d.w};
#pragma unroll
            for (int t = 0; t < 4; ++t) {
                int a = ss[t], bb = dd[t];
                bool atgt = hexists(hkey, a);
                bool btgt = (bb == a) ? atgt : hexists(hkey, bb);
                if (!atgt && !btgt) continue;
                int e = e4 * 4 + t;
                if (atgt) hemit_g(hkey, hval, P.cnt, P.lst, a, e, bb | (btgt ? TFLAG : 0));
                if (btgt && bb != a) hemit_g(hkey, hval, P.cnt, P.lst, bb, e, a | (atgt ? TFLAG : 0));
            }
        }
    }
    gbar(P.bar, NBLK, true);

    // ================= layer phases =================
    const float scale = 0.17677669529663687f;  // 1/sqrt(32)
    const int u = P.tp[b];
    const int c = min(P.cnt[b], CAP);

    for (int layer = 0; layer < 2; ++layer) {
        const float* WT_in = P.WT;
        const float* WT_ft = P.WT + (1 + layer) * MSTRIDE;
        const float* WT_te2 = P.WT + (3 + layer) * MSTRIDE;
        const float* WT_q = P.WT + (5 + 3 * layer) * MSTRIDE;
        const float* WT_k = P.WT + (6 + 3 * layer) * MSTRIDE;
        const float* WT_v = P.WT + (7 + 3 * layer) * MSTRIDE;
        const float* WT_ao = P.WT + (11 + layer) * MSTRIDE;
        const float* WT_op = P.WT + (13 + layer) * MSTRIDE;
        const float* inb = P.inb;
        const float* ftb = P.ftb + layer * 128;
        const float* teW1 = P.teW1 + layer * 128;
        const float* teb1 = P.teb1 + layer * 128;
        const float* teb2 = P.teb2 + layer * 128;
        const float* bq = P.aib + layer * 384;
        const float* bk = bq + 128;
        const float* bv = bq + 256;
        const float* aob = P.aob + layer * 128;
        const float* opb = P.opb + layer * 128;

        // ---- phase A (register-chained: 1 barrier per matvec) ----
        float4 xva[4];
        {
            const float* xsrc = (layer == 0) ? (P.nf + (size_t)u * 128)
                                             : (P.x + (size_t)u * 128);
#pragma unroll
            for (int cc = 0; cc < 4; ++cc)
                xva[cc] = *(const float4*)(xsrc + (g * 4 + cc) * 4);
        }
        if (layer == 0) {
            pbA[g * 32 + jj] = mv_reg_g8(WT_in, xva, g, jj);
            __syncthreads();
            comb_wave(pbA, g, jj, inb, xva);        // xva = x0 chunk
        }
        pbB[g * 32 + jj] = mv_reg_g8(WT_ft, xva, g, jj);
        __syncthreads();
        float4 xvt[4];
        comb_wave(pbB, g, jj, ftb, xvt);            // tf chunk
        store_chunk(tfv, g, jj, xvt);               // for epilogue fallback
        pbA[g * 32 + jj] = mv_reg_g8(WT_q, xvt, g, jj);
        __syncthreads();
        {
            float4 xvq[4];
            comb_wave(pbA, g, jj, bq, xvq);
            store_chunk(qv, g, jj, xvq);            // consumed in phase B (after syncs)
        }

        // ---- phase B: batches of 16, acc[16] matvecs (r9 form) ----
        for (int base = 0; base < c; base += BATCH) {
            if (tid < BATCH) {
                int i = base + tid;
                int2 en = (i < c) ? P.lst[b * CAP + i] : make_int2(0, 0);
                nbr_s[tid] = en.y & ~TFLAG;
                tf_s[tid] = (en.y & TFLAG) ? 1 : 0;
                ts_s[tid] = (i < c) ? P.ts[en.x] : 0.f;
            }
            __syncthreads();
            {   // stage 16 neighbor rows + te layer-1 activations (2 rows/group)
                int c0 = jj * 4;
                float4 w = *(const float4*)(teW1 + c0);
                float4 bb = *(const float4*)(teb1 + c0);
#pragma unroll
                for (int s = 0; s < 2; ++s) {
                    int e = g + s * 8;
                    const float* srcp = (layer == 0) ? (P.nf + (size_t)nbr_s[e] * 128 + c0)
                                                     : (P.x + (size_t)nbr_s[e] * 128 + c0);
                    float4 v = *(const float4*)srcp;
                    float* dstp = (layer == 0) ? xs : x0s;
                    *(float4*)(dstp + e * 128 + c0) = v;
                    float tse = ts_s[e];
                    *(float4*)(t1s + e * 128 + c0) =
                        make_float4(fmaxf(fmaf(tse, w.x, bb.x), 0.f),
                                    fmaxf(fmaf(tse, w.y, bb.y), 0.f),
                                    fmaxf(fmaf(tse, w.z, bb.z), 0.f),
                                    fmaxf(fmaf(tse, w.w, bb.w), 0.f));
                }
            }
            __syncthreads();
            if (layer == 0) {  // x0_nbr = inW @ nf[nbr] + inb; persist relu(x0)
                float4 acc[16] = {F4Z, F4Z, F4Z, F4Z, F4Z, F4Z, F4Z, F4Z,
                                  F4Z, F4Z, F4Z, F4Z, F4Z, F4Z, F4Z, F4Z};
                mv16_g8(WT_in, xs, g, jj, acc);
#pragma unroll
                for (int e = 0; e < 16; ++e) pb[(g * 16 + e) * 32 + jj] = acc[e];
                __syncthreads();
#pragma unroll
                for (int s = 0; s < 2; ++s) {
                    int it = 2 * g + s;
                    float4 x0v = add4(comb16_g8(pb, it, jj), *(const float4*)(inb + jj * 4));
                    *(float4*)(x0s + it * 128 + jj * 4) = x0v;
                    // skip target rows (their final value is relu(agg))
                    if (base + it < c && !tf_s[it])
                        *(float4*)(P.x + (size_t)nbr_s[it] * 128 + jj * 4) = relu4(x0v);
                }
                __syncthreads();
            }
            {   // z = ftW@x0 + teW2@t1 + biases (fused accumulation, one comb)
                float4 acc[16] = {F4Z, F4Z, F4Z, F4Z, F4Z, F4Z, F4Z, F4Z,
                                  F4Z, F4Z, F4Z, F4Z, F4Z, F4Z, F4Z, F4Z};
                mv16_g8(WT_ft, x0s, g, jj, acc);
                mv16_g8(WT_te2, t1s, g, jj, acc);   // accumulates into same acc
#pragma unroll
                for (int e = 0; e < 16; ++e) pb[(g * 16 + e) * 32 + jj] = acc[e];
                __syncthreads();
                float4 zb4 = add4(*(const float4*)(ftb + jj * 4),
                                  *(const float4*)(teb2 + jj * 4));
#pragma unroll
                for (int s = 0; s < 2; ++s) {
                    int it = 2 * g + s;
                    *(float4*)(zs + it * 128 + jj * 4) = add4(comb16_g8(pb, it, jj), zb4);
                }
                __syncthreads();
            }
            {   // K: scores
                float4 acc[16] = {F4Z, F4Z, F4Z, F4Z, F4Z, F4Z, F4Z, F4Z,
                                  F4Z, F4Z, F4Z, F4Z, F4Z, F4Z, F4Z, F4Z};
                mv16_g8(WT_k, zs, g, jj, acc);
#pragma unroll
                for (int e = 0; e < 16; ++e) pb[(g * 16 + e) * 32 + jj] = acc[e];
                __syncthreads();
                float4 q4 = *(const float4*)(qv + jj * 4);
#pragma unroll
                for (int s = 0; s < 2; ++s) {
                    int it = 2 * g + s;
                    float4 kk = add4(comb16_g8(pb, it, jj), *(const float4*)(bk + jj * 4));
                    float pr = q4.x * kk.x + q4.y * kk.y + q4.z * kk.z + q4.w * kk.w;
                    pr += __shfl_xor(pr, 1);
                    pr += __shfl_xor(pr, 2);
                    pr += __shfl_xor(pr, 4);  // sum over the 8 lanes of head jj>>3
                    if (base + it < c && (jj & 7) == 0)
                        scl[(base + it) * 4 + (jj >> 3)] = pr * scale;
                }
                __syncthreads();
            }
            {   // V
                float4 acc[16] = {F4Z, F4Z, F4Z, F4Z, F4Z, F4Z, F4Z, F4Z,
                                  F4Z, F4Z, F4Z, F4Z, F4Z, F4Z, F4Z, F4Z};
                mv16_g8(WT_v, zs, g, jj, acc);
#pragma unroll
                for (int e = 0; e < 16; ++e) pb[(g * 16 + e) * 32 + jj] = acc[e];
                __syncthreads();
#pragma unroll
                for (int s = 0; s < 2; ++s) {
                    int it = 2 * g + s;
                    float4 vv = add4(comb16_g8(pb, it, jj), *(const float4*)(bv + jj * 4));
                    if (base + it < c)
                        *(float4*)(vbl + (base + it) * 128 + jj * 4) = vv;
                }
                __syncthreads();  // before next batch restages LDS
            }
        }

        // ---- fused reduce: softmax over LDS scores + weighted v-sum ----
        if (tid < 128) {
            int hd = tid >> 5;
            if (c > 0) {
                float m = -INFINITY;
                for (int i = 0; i < c; ++i) m = fmaxf(m, scl[i * 4 + hd]);
                float l = 0.f, o = 0.f;
                for (int i = 0; i < c; ++i) {
                    float p = __expf(scl[i * 4 + hd] - m);
                    l += p;
                    o = fmaf(p, vbl[i * 128 + tid], o);
                }
                sv[tid] = o / l;
            } else {
                sv[tid] = 0.f;
            }
        }
        __syncthreads();
        // ---- epilogue (register-chained) ----
        float4 xvz[4];
        {
            float4 xvs[4];
#pragma unroll
            for (int cc = 0; cc < 4; ++cc)
                xvs[cc] = *(const float4*)(sv + (g * 4 + cc) * 4);
            pbA[g * 32 + jj] = mv_reg_g8(WT_ao, xvs, g, jj);
        }
        __syncthreads();
        comb_wave(pbA, g, jj, aob, xvz);
        if (c == 0) {  // no neighbors: z = tfv
#pragma unroll
            for (int cc = 0; cc < 4; ++cc)
                xvz[cc] = *(const float4*)(tfv + (g * 4 + cc) * 4);
        }
        pbB[g * 32 + jj] = mv_reg_g8(WT_op, xvz, g, jj);
        __syncthreads();
        comb_wave(pbB, g, jj, opb, xvz);
#pragma unroll
        for (int cc = 0; cc < 4; ++cc) xvz[cc] = relu4(xvz[cc]);
        if (layer == 0) {
            if ((jj & 7) == 0)
                *(float4*)(P.x + (size_t)u * 128 + (g * 4 + (jj >> 3)) * 4) = xvz[jj >> 3];
        } else {
            // layer 1: emb head
            pbA[g * 32 + jj] = mv_reg_g8(P.WT + 15 * MSTRIDE, xvz, g, jj);
            __syncthreads();
            comb_wave(pbA, g, jj, P.o1b, xvz);
#pragma unroll
            for (int cc = 0; cc < 4; ++cc) xvz[cc] = relu4(xvz[cc]);
            pbB[g * 32 + jj] = mv_reg_g8_64(P.WT + 17 * MSTRIDE, xvz, g, jj);
            __syncthreads();
            if (g == 0 && jj < 16)
                *(float4*)(P.emb + (size_t)b * 64 + jj * 4) =
                    add4(comb1_g8(pbB, jj), *(const float4*)(P.o2b + jj * 4));
        }
        // last barrier: blocks that don't run the pair head arrive-only
        gbar(P.bar, NBLK * (2 + layer), layer == 0 || b < N_PAIRS);
    }

    // ================= pair head (blocks 0..127) =================
    if (b < N_PAIRS) {
        const float* WT_l1 = P.WT + 16 * MSTRIDE;
        const float* WT_l2 = P.WT + 18 * MSTRIDE;
        if (tid < 128)
            xu[tid] = (tid < 64) ? P.emb[(size_t)(2 * b) * 64 + tid]
                                 : P.emb[(size_t)(2 * b + 1) * 64 + (tid - 64)];
        __syncthreads();
        if (tid < 128) pb[g * 32 + jj] = mv_ks1(WT_l1, xu, g, jj);
        __syncthreads();
        if (tid < 128 && g == 0)
            *(float4*)(tfv + jj * 4) =
                relu4(add4(comb1(pb, jj), *(const float4*)(P.l1b + jj * 4)));
        __syncthreads();
        if (tid < 128) pb[g * 32 + jj] = mv_ks1_64(WT_l2, tfv, g, jj);
        __syncthreads();
        if (tid < 128 && g == 0 && jj < 16)
            *(float4*)(qv + jj * 4) =
                relu4(add4(comb1(pb, jj), *(const float4*)(P.l2b + jj * 4)));
        __syncthreads();
        if (tid < 64) {
            float v = qv[tid] * P.l3W[tid];
            v += __shfl_xor(v, 1);
            v += __shfl_xor(v, 2);
            v += __shfl_xor(v, 4);
            v += __shfl_xor(v, 8);
            v += __shfl_xor(v, 16);
            v += __shfl_xor(v, 32);
            if (tid == 0) P.out[b] = 1.f / (1.f + __expf(-(v + P.l3b[0])));
        }
    }
}

// ---------- launch ----------
extern "C" void kernel_launch(void* const* d_in, const int* in_sizes, int n_in,
                              void* d_out, int out_size, void* d_ws, size_t ws_size,
                              hipStream_t stream) {
    Params P;
    P.nf  = (const float*)d_in[0];
    P.ei  = (const int*)d_in[1];
    P.ts  = (const float*)d_in[2];
    P.tp  = (const int*)d_in[3];
    P.inW = (const float*)d_in[4];
    P.inb = (const float*)d_in[5];
    P.teW1 = (const float*)d_in[6];
    P.teb1 = (const float*)d_in[7];
    P.teW2 = (const float*)d_in[8];
    P.teb2 = (const float*)d_in[9];
    P.aiW = (const float*)d_in[10];
    P.aib = (const float*)d_in[11];
    P.aoW = (const float*)d_in[12];
    P.aob = (const float*)d_in[13];
    P.ftW = (const float*)d_in[14];
    P.ftb = (const float*)d_in[15];
    P.opW = (const float*)d_in[16];
    P.opb = (const float*)d_in[17];
    P.o1W = (const float*)d_in[18];
    P.o1b = (const float*)d_in[19];
    P.o2W = (const float*)d_in[20];
    P.o2b = (const float*)d_in[21];
    P.l1W = (const float*)d_in[22];
    P.l1b = (const float*)d_in[23];
    P.l2W = (const float*)d_in[24];
    P.l2b = (const float*)d_in[25];
    P.l3W = (const float*)d_in[26];
    P.l3b = (const float*)d_in[27];
    P.out = (float*)d_out;

    char* ws = (char*)d_ws;
    size_t off = 0;
    P.x    = (float*)(ws + off); off += (size_t)N_NODES * 128 * 4;   // 10.24 MB
    P.cnt  = (int*)  (ws + off); off += N_SLOTS * 4;
    P.lst  = (int2*) (ws + off); off += (size_t)N_SLOTS * CAP * 8;
    P.emb  = (float*)(ws + off); off += N_SLOTS * 64 * 4;
    P.WT   = (float*)(ws + off); off += (size_t)NMAT * MSTRIDE * 4;  // 1.2 MB
    P.bar  = (unsigned*)(ws + off); off += 256;                      // grid barrier

    hipMemsetAsync(P.cnt, 0, N_SLOTS * 4, stream);  // scan uses global counters
    hipMemsetAsync(P.bar, 0, 4, stream);
    k_fused<<<NBLK, 256, 0, stream>>>(P);
}

// Round 12
// 195.926 us; speedup vs baseline: 1.0525x; 1.0525x over previous
//
#include <hip/hip_runtime.h>
#include <math.h>

#define N_NODES 20000
#define N_EDGES 50000
#define N_SLOTS 256   // N_PAIRS * 2 flattened targets
#define N_PAIRS 128
#define CAP 32        // max incident edges per slot (deg ~ Poisson(5); P(>=32)~1e-16)
#define MSTRIDE 16384 // floats per transposed-matrix slot in ws
#define NMAT 19
#define TFLAG (1 << 30)
#define HSZ 1024      // LDS hash table size (load factor 0.25)
#define NBLK 256
#define BATCH 16      // phase-B edge batch: one batch covers ~every slot

// ---------- helpers ----------
__device__ __forceinline__ float4 relu4(float4 v) {
    return make_float4(fmaxf(v.x, 0.f), fmaxf(v.y, 0.f), fmaxf(v.z, 0.f), fmaxf(v.w, 0.f));
}
__device__ __forceinline__ float4 add4(float4 a, float4 b) {
    return make_float4(a.x + b.x, a.y + b.y, a.z + b.z, a.w + b.w);
}
__device__ __forceinline__ void fma4(float4& acc, const float4 w, const float s) {
    acc.x = fmaf(w.x, s, acc.x); acc.y = fmaf(w.y, s, acc.y);
    acc.z = fmaf(w.z, s, acc.z); acc.w = fmaf(w.w, s, acc.w);
}
#define F4Z make_float4(0.f, 0.f, 0.f, 0.f)

// manual grid barrier (r4: coherence-point poll; r6: split release/acquire
// fences). Lessons: r7/r8 512-thr blocks cap VGPR at 128 -> spills; r10
// weight preload defeats compiler pipelining; r11 shuffle-combine adds
// bank conflicts. r12 = r9 structure + algebraic K/V elimination.
__device__ __forceinline__ void gbar(unsigned* cnt, unsigned target, bool wait) {
    __syncthreads();
    if (threadIdx.x == 0) {
        __builtin_amdgcn_fence(__ATOMIC_RELEASE, "agent");  // wbl2, no inv
        __hip_atomic_fetch_add(cnt, 1u, __ATOMIC_RELAXED, __HIP_MEMORY_SCOPE_AGENT);
        if (wait) {
            int it = 0;
            while (true) {
                unsigned v;
                if ((it++ & 7) != 7)
                    v = __hip_atomic_load(cnt, __ATOMIC_RELAXED,
                                          __HIP_MEMORY_SCOPE_SYSTEM);
                else
                    v = __hip_atomic_fetch_add(cnt, 0u, __ATOMIC_RELAXED,
                                               __HIP_MEMORY_SCOPE_AGENT);
                if (v >= target) break;
                __builtin_amdgcn_s_sleep(16);
            }
            __builtin_amdgcn_fence(__ATOMIC_ACQUIRE, "agent");  // single inv
        }
    }
    __syncthreads();
}

// ===== 8-group K-split (256 threads): group g covers k-chunks [4g,4g+4) =====
__device__ __forceinline__ float4 mv_ks1_g8(const float* __restrict__ WT,
                                            const float* __restrict__ xv128,
                                            int g, int jj) {
    const float4* W4 = (const float4*)WT;
    const float4* x4 = (const float4*)xv128;
    float4 acc = F4Z;
#pragma unroll
    for (int kk4 = 0; kk4 < 4; ++kk4) {
        int k4 = g * 4 + kk4;
        float4 xv = x4[k4];
        fma4(acc, W4[(k4 * 4 + 0) * 32 + jj], xv.x);
        fma4(acc, W4[(k4 * 4 + 1) * 32 + jj], xv.y);
        fma4(acc, W4[(k4 * 4 + 2) * 32 + jj], xv.z);
        fma4(acc, W4[(k4 * 4 + 3) * 32 + jj], xv.w);
    }
    return acc;
}
// 64-output variant (WT stored [128][64]); lanes jj>=16 compute duplicates
__device__ __forceinline__ float4 mv_ks1_g8_64(const float* __restrict__ WT,
                                               const float* __restrict__ xv128,
                                               int g, int jj) {
    const float4* W4 = (const float4*)WT;
    const float4* x4 = (const float4*)xv128;
    int j16 = jj & 15;
    float4 acc = F4Z;
#pragma unroll
    for (int kk4 = 0; kk4 < 4; ++kk4) {
        int k4 = g * 4 + kk4;
        float4 xv = x4[k4];
        fma4(acc, W4[(k4 * 4 + 0) * 16 + j16], xv.x);
        fma4(acc, W4[(k4 * 4 + 1) * 16 + j16], xv.y);
        fma4(acc, W4[(k4 * 4 + 2) * 16 + j16], xv.z);
        fma4(acc, W4[(k4 * 4 + 3) * 16 + j16], xv.w);
    }
    return acc;
}
__device__ __forceinline__ float4 comb1_g8(const float4* pb, int jj) {
    float4 s = pb[jj];
#pragma unroll
    for (int gp = 1; gp < 8; ++gp) s = add4(s, pb[gp * 32 + jj]);
    return s;
}

// ===== 16-item, 8-group matvec (r9 form — compiler pipelines loads) =====
__device__ __forceinline__ void mv16_g8(const float* __restrict__ WT,
                                        const float* __restrict__ xs,
                                        int g, int jj, float4* acc) {
    const float4* W4 = (const float4*)WT;
    const float4* x4 = (const float4*)xs;
#pragma unroll
    for (int kk4 = 0; kk4 < 4; ++kk4) {
        int k4 = g * 4 + kk4;
        float4 w0 = W4[(k4 * 4 + 0) * 32 + jj];
        float4 w1 = W4[(k4 * 4 + 1) * 32 + jj];
        float4 w2 = W4[(k4 * 4 + 2) * 32 + jj];
        float4 w3 = W4[(k4 * 4 + 3) * 32 + jj];
#pragma unroll
        for (int e = 0; e < 16; ++e) {
            float4 xv = x4[e * 32 + k4];
            fma4(acc[e], w0, xv.x); fma4(acc[e], w1, xv.y);
            fma4(acc[e], w2, xv.z); fma4(acc[e], w3, xv.w);
        }
    }
}
__device__ __forceinline__ float4 comb16_g8(const float4* pb, int it, int jj) {
    float4 s = pb[it * 32 + jj];
#pragma unroll
    for (int gp = 1; gp < 8; ++gp) s = add4(s, pb[(gp * 16 + it) * 32 + jj]);
    return s;
}

// ===== 4-group variants for the 128-thread pair head =====
__device__ __forceinline__ float4 mv_ks1(const float* __restrict__ WT,
                                         const float* __restrict__ xv128,
                                         int g, int jj) {
    const float4* W4 = (const float4*)WT;
    const float4* x4 = (const float4*)xv128;
    float4 acc = F4Z;
#pragma unroll 2
    for (int kk4 = 0; kk4 < 8; ++kk4) {
        int k4 = g * 8 + kk4;
        float4 xv = x4[k4];
        fma4(acc, W4[(k4 * 4 + 0) * 32 + jj], xv.x);
        fma4(acc, W4[(k4 * 4 + 1) * 32 + jj], xv.y);
        fma4(acc, W4[(k4 * 4 + 2) * 32 + jj], xv.z);
        fma4(acc, W4[(k4 * 4 + 3) * 32 + jj], xv.w);
    }
    return acc;
}
__device__ __forceinline__ float4 mv_ks1_64(const float* __restrict__ WT,
                                            const float* __restrict__ xv128,
                                            int g, int jj) {
    const float4* W4 = (const float4*)WT;
    const float4* x4 = (const float4*)xv128;
    int j16 = jj & 15;
    float4 acc = F4Z;
#pragma unroll 2
    for (int kk4 = 0; kk4 < 8; ++kk4) {
        int k4 = g * 8 + kk4;
        float4 xv = x4[k4];
        fma4(acc, W4[(k4 * 4 + 0) * 16 + j16], xv.x);
        fma4(acc, W4[(k4 * 4 + 1) * 16 + j16], xv.y);
        fma4(acc, W4[(k4 * 4 + 2) * 16 + j16], xv.z);
        fma4(acc, W4[(k4 * 4 + 3) * 16 + j16], xv.w);
    }
    return acc;
}
__device__ __forceinline__ float4 comb1(const float4* pb, int jj) {
    return add4(add4(pb[jj], pb[32 + jj]), add4(pb[64 + jj], pb[96 + jj]));
}

// ---------- hash helpers ----------
__device__ __forceinline__ unsigned thash(int key) {
    return ((unsigned)key * 2654435761u) >> 22;
}
__device__ __forceinline__ bool hexists(const int* __restrict__ hkey, int key) {
    unsigned h = thash(key);
    while (true) {
        int k = hkey[h];
        if (k == -1) return false;
        if (k == key) return true;
        h = (h + 1) & (HSZ - 1);
    }
}
__device__ __forceinline__ void hemit_g(const int* __restrict__ hkey,
                                        const int* __restrict__ hval,
                                        int* __restrict__ gcnt,
                                        int2* __restrict__ lst,
                                        int key, int e, int nbrf) {
    unsigned h = thash(key);
    while (true) {
        int k = hkey[h];
        if (k == -1) return;
        if (k == key) {
            int s = hval[h];
            int pos = atomicAdd(&gcnt[s], 1);
            if (pos < CAP) lst[s * CAP + pos] = make_int2(e, nbrf);
        }
        h = (h + 1) & (HSZ - 1);
    }
}

// ---------- params ----------
struct Params {
    const float* nf; const int* ei; const float* ts; const int* tp;
    const float* inW; const float* inb;
    const float* teW1; const float* teb1; const float* teW2; const float* teb2;
    const float* aiW; const float* aib; const float* aoW; const float* aob;
    const float* ftW; const float* ftb; const float* opW; const float* opb;
    const float* o1W; const float* o1b; const float* o2W; const float* o2b;
    const float* l1W; const float* l1b; const float* l2W; const float* l2b;
    const float* l3W; const float* l3b;
    float* out; float* x; int* cnt; int2* lst; float* emb; float* WT;
    unsigned* bar;
};

// r12: r9 base + algebraic elimination of phase-B K and V matvecs:
//   score:  q.(Wk z + bk) = (Wk_h^T q).z + q_h.bk_h   (qkh precomputed/layer)
//   value:  sum_e p_e (Wv z_e + bv) = Wv_h (sum_e p_e z_e) + bv  (p sums to 1)
// Phase B per batch: stage / [L0: in mv16] / ft+te2 mv16 / 4 dot-products.
__global__ __launch_bounds__(256, 1) void k_fused(Params P) {
    __shared__ __align__(16) float xu[128], x0u[128], tfv[128], qv[128], sv[128];
    __shared__ __align__(16) float xs[BATCH * 128], t1s[BATCH * 128];
    __shared__ __align__(16) float x0s[BATCH * 128];
    __shared__ __align__(16) float zs[CAP * 128];     // 16 KB: z for ALL items
    __shared__ __align__(16) float4 pb[8 * 16 * 32];  // 64 KB partials
    __shared__ __align__(16) float qkh[4 * 128];      // per-head Wk^T q
    __shared__ __align__(16) float zbl[4 * 128];      // per-head weighted z-sum
    __shared__ float scl[CAP * 4], ps[CAP * 4], sbk[4];
    __shared__ int nbr_s[BATCH], tf_s[BATCH];
    __shared__ float ts_s[BATCH];
    __shared__ __align__(16) float tile[32][129];     // prep: transpose staging
    __shared__ int hkey[HSZ], hval[HSZ];              // prep: target hash

    const int b = blockIdx.x, tid = threadIdx.x, g = tid >> 5, jj = tid & 31;

    // ================= prep phase =================
    if (b < 72) {  // weight transposes
        int m, r0, rows;
        if (b < 68) { m = b >> 2; r0 = (b & 3) * 32; rows = 128; }
        else { int mm = b - 68; m = 17 + (mm >> 1); r0 = (mm & 1) * 32; rows = 64; }
        const float* src;
        if (m == 0) src = P.inW;
        else if (m <= 2) src = P.ftW + (m - 1) * MSTRIDE;
        else if (m <= 4) src = P.teW2 + (m - 3) * MSTRIDE;
        else if (m <= 10) src = P.aiW + (m - 5) * MSTRIDE;  // q0,k0,v0,q1,k1,v1
        else if (m <= 12) src = P.aoW + (m - 11) * MSTRIDE;
        else if (m <= 14) src = P.opW + (m - 13) * MSTRIDE;
        else if (m == 15) src = P.o1W;
        else if (m == 16) src = P.l1W;
        else if (m == 17) src = P.o2W;
        else src = P.l2W;
        float* dst = P.WT + m * MSTRIDE;
        for (int idx = tid; idx < 32 * 128; idx += 256) {
            int r = idx >> 7, cc = idx & 127;
            tile[r][cc] = src[(r0 + r) * 128 + cc];
        }
        __syncthreads();
        for (int idx = tid; idx < 128 * 32; idx += 256) {
            int k = idx >> 5, jr = idx & 31;
            dst[k * rows + r0 + jr] = tile[jr][k];
        }
    } else {
        // blocks 72..255: distributed O(E) hash scan, global-atomic emits.
        for (int i = tid; i < HSZ; i += 256) hkey[i] = -1;
        __syncthreads();
        {   // insert all 256 (target, slot) pairs, duplicates get own cells
            int uu = P.tp[tid];
            unsigned h = thash(uu);
            while (atomicCAS(&hkey[h], -1, uu) != -1) h = (h + 1) & (HSZ - 1);
            hval[h] = tid;
        }
        __syncthreads();
        const int4* s4 = (const int4*)P.ei;
        const int4* d4 = (const int4*)(P.ei + N_EDGES);
        const int NE4 = N_EDGES / 4;                     // 12500
        const int nscan = NBLK - 72;                     // 184 scan blocks
        const int chunk = (NE4 + nscan - 1) / nscan;     // 68
        const int start = (b - 72) * chunk;
        const int end = min(start + chunk, NE4);
        for (int e4 = start + tid; e4 < end; e4 += 256) {
            int4 s = s4[e4];
            int4 d = d4[e4];
            int ss[4] = {s.x, s.y, s.z, s.w};
            int dd[4] = {d.x, d.y, d.z, d.w};
#pragma unroll
            for (int t = 0; t < 4; ++t) {
                int a = ss[t], bb = dd[t];
                bool atgt = hexists(hkey, a);
                bool btgt = (bb == a) ? atgt : hexists(hkey, bb);
                if (!atgt && !btgt) continue;
                int e = e4 * 4 + t;
                if (atgt) hemit_g(hkey, hval, P.cnt, P.lst, a, e, bb | (btgt ? TFLAG : 0));
                if (btgt && bb != a) hemit_g(hkey, hval, P.cnt, P.lst, bb, e, a | (atgt ? TFLAG : 0));
            }
        }
    }
    gbar(P.bar, NBLK, true);

    // ================= layer phases =================
    const float scale = 0.17677669529663687f;  // 1/sqrt(32)
    const int u = P.tp[b];
    const int c = min(P.cnt[b], CAP);

    for (int layer = 0; layer < 2; ++layer) {
        const float* WT_in = P.WT;
        const float* WT_ft = P.WT + (1 + layer) * MSTRIDE;
        const float* WT_te2 = P.WT + (3 + layer) * MSTRIDE;
        const float* WT_q = P.WT + (5 + 3 * layer) * MSTRIDE;
        const float* WT_v = P.WT + (7 + 3 * layer) * MSTRIDE;
        const float* WT_ao = P.WT + (11 + layer) * MSTRIDE;
        const float* WT_op = P.WT + (13 + layer) * MSTRIDE;
        const float* inb = P.inb;
        const float* ftb = P.ftb + layer * 128;
        const float* teW1 = P.teW1 + layer * 128;
        const float* teb1 = P.teb1 + layer * 128;
        const float* teb2 = P.teb2 + layer * 128;
        const float* bq = P.aib + layer * 384;
        const float* bk = bq + 128;
        const float* bv = bq + 256;
        const float* aob = P.aob + layer * 128;
        const float* opb = P.opb + layer * 128;

        // ---- phase A ----
        if (tid < 128) xu[tid] = (layer == 0) ? P.nf[(size_t)u * 128 + tid]
                                              : P.x[(size_t)u * 128 + tid];
        __syncthreads();
        const float* xeff = xu;
        if (layer == 0) {
            pb[g * 32 + jj] = mv_ks1_g8(WT_in, xu, g, jj);
            __syncthreads();
            if (g == 0)
                *(float4*)(x0u + jj * 4) = add4(comb1_g8(pb, jj), *(const float4*)(inb + jj * 4));
            xeff = x0u;
            __syncthreads();
        }
        pb[g * 32 + jj] = mv_ks1_g8(WT_ft, xeff, g, jj);
        __syncthreads();
        if (g == 0)
            *(float4*)(tfv + jj * 4) = add4(comb1_g8(pb, jj), *(const float4*)(ftb + jj * 4));
        __syncthreads();
        pb[g * 32 + jj] = mv_ks1_g8(WT_q, tfv, g, jj);
        __syncthreads();
        if (g == 0)
            *(float4*)(qv + jj * 4) = add4(comb1_g8(pb, jj), *(const float4*)(bq + jj * 4));
        __syncthreads();
        // ---- qkh = per-head Wk^T q (raw Wk layout, coalesced), sbk = q_h.bk_h ----
        {
            const float* WkRaw = P.aiW + (size_t)layer * 3 * MSTRIDE + MSTRIDE;
            int i = tid & 127, hb = tid >> 7;
#pragma unroll
            for (int s = 0; s < 2; ++s) {
                int h = hb * 2 + s;
                float a = 0.f;
#pragma unroll 8
                for (int j = 0; j < 32; ++j)
                    a = fmaf(WkRaw[(size_t)(h * 32 + j) * 128 + i], qv[h * 32 + j], a);
                qkh[h * 128 + i] = a;
            }
            if (tid < 128) {
                float pp = qv[tid] * bk[tid];
                pp += __shfl_xor(pp, 1, 32); pp += __shfl_xor(pp, 2, 32);
                pp += __shfl_xor(pp, 4, 32); pp += __shfl_xor(pp, 8, 32);
                pp += __shfl_xor(pp, 16, 32);
                if ((tid & 31) == 0) sbk[tid >> 5] = pp;
            }
        }
        __syncthreads();

        // ---- phase B: batches of 16; z matvec + score dot products only ----
        for (int base = 0; base < c; base += BATCH) {
            if (tid < BATCH) {
                int i = base + tid;
                int2 en = (i < c) ? P.lst[b * CAP + i] : make_int2(0, 0);
                nbr_s[tid] = en.y & ~TFLAG;
                tf_s[tid] = (en.y & TFLAG) ? 1 : 0;
                ts_s[tid] = (i < c) ? P.ts[en.x] : 0.f;
            }
            __syncthreads();
            {   // stage 16 neighbor rows + te layer-1 activations (2 rows/group)
                int c0 = jj * 4;
                float4 w = *(const float4*)(teW1 + c0);
                float4 bb = *(const float4*)(teb1 + c0);
#pragma unroll
                for (int s = 0; s < 2; ++s) {
                    int e = g + s * 8;
                    const float* srcp = (layer == 0) ? (P.nf + (size_t)nbr_s[e] * 128 + c0)
                                                     : (P.x + (size_t)nbr_s[e] * 128 + c0);
                    float4 v = *(const float4*)srcp;
                    float* dstp = (layer == 0) ? xs : x0s;
                    *(float4*)(dstp + e * 128 + c0) = v;
                    float tse = ts_s[e];
                    *(float4*)(t1s + e * 128 + c0) =
                        make_float4(fmaxf(fmaf(tse, w.x, bb.x), 0.f),
                                    fmaxf(fmaf(tse, w.y, bb.y), 0.f),
                                    fmaxf(fmaf(tse, w.z, bb.z), 0.f),
                                    fmaxf(fmaf(tse, w.w, bb.w), 0.f));
                }
            }
            __syncthreads();
            if (layer == 0) {  // x0_nbr = inW @ nf[nbr] + inb; persist relu(x0)
                float4 acc[16] = {F4Z, F4Z, F4Z, F4Z, F4Z, F4Z, F4Z, F4Z,
                                  F4Z, F4Z, F4Z, F4Z, F4Z, F4Z, F4Z, F4Z};
                mv16_g8(WT_in, xs, g, jj, acc);
#pragma unroll
                for (int e = 0; e < 16; ++e) pb[(g * 16 + e) * 32 + jj] = acc[e];
                __syncthreads();
#pragma unroll
                for (int s = 0; s < 2; ++s) {
                    int it = 2 * g + s;
                    float4 x0v = add4(comb16_g8(pb, it, jj), *(const float4*)(inb + jj * 4));
                    *(float4*)(x0s + it * 128 + jj * 4) = x0v;
                    // skip target rows (their final value is relu(agg))
                    if (base + it < c && !tf_s[it])
                        *(float4*)(P.x + (size_t)nbr_s[it] * 128 + jj * 4) = relu4(x0v);
                }
                __syncthreads();
            }
            {   // z = ftW@x0 + teW2@t1 + biases (fused acc, one comb) -> zs[abs]
                float4 acc[16] = {F4Z, F4Z, F4Z, F4Z, F4Z, F4Z, F4Z, F4Z,
                                  F4Z, F4Z, F4Z, F4Z, F4Z, F4Z, F4Z, F4Z};
                mv16_g8(WT_ft, x0s, g, jj, acc);
                mv16_g8(WT_te2, t1s, g, jj, acc);
#pragma unroll
                for (int e = 0; e < 16; ++e) pb[(g * 16 + e) * 32 + jj] = acc[e];
                __syncthreads();
                float4 zb4 = add4(*(const float4*)(ftb + jj * 4),
                                  *(const float4*)(teb2 + jj * 4));
#pragma unroll
                for (int s = 0; s < 2; ++s) {
                    int it = 2 * g + s;
                    *(float4*)(zs + (size_t)(base + it) * 128 + jj * 4) =
                        add4(comb16_g8(pb, it, jj), zb4);
                }
                __syncthreads();
            }
            {   // scores: s_h = (qkh[h].z + sbk[h]) * scale   (16 thr/item)
                int it = tid >> 4, l = tid & 15, item = base + it;
                const float* zp = zs + (size_t)item * 128;
                float s0 = 0.f, s1 = 0.f, s2 = 0.f, s3 = 0.f;
#pragma unroll
                for (int dd = 0; dd < 8; ++dd) {
                    int d = dd * 16 + l;
                    float zv = zp[d];
                    s0 = fmaf(qkh[d], zv, s0);
                    s1 = fmaf(qkh[128 + d], zv, s1);
                    s2 = fmaf(qkh[256 + d], zv, s2);
                    s3 = fmaf(qkh[384 + d], zv, s3);
                }
                s0 += __shfl_xor(s0, 1, 16); s0 += __shfl_xor(s0, 2, 16);
                s0 += __shfl_xor(s0, 4, 16); s0 += __shfl_xor(s0, 8, 16);
                s1 += __shfl_xor(s1, 1, 16); s1 += __shfl_xor(s1, 2, 16);
                s1 += __shfl_xor(s1, 4, 16); s1 += __shfl_xor(s1, 8, 16);
                s2 += __shfl_xor(s2, 1, 16); s2 += __shfl_xor(s2, 2, 16);
                s2 += __shfl_xor(s2, 4, 16); s2 += __shfl_xor(s2, 8, 16);
                s3 += __shfl_xor(s3, 1, 16); s3 += __shfl_xor(s3, 2, 16);
                s3 += __shfl_xor(s3, 4, 16); s3 += __shfl_xor(s3, 8, 16);
                if (l == 0 && item < c) {
                    scl[item * 4 + 0] = (s0 + sbk[0]) * scale;
                    scl[item * 4 + 1] = (s1 + sbk[1]) * scale;
                    scl[item * 4 + 2] = (s2 + sbk[2]) * scale;
                    scl[item * 4 + 3] = (s3 + sbk[3]) * scale;
                }
                __syncthreads();  // before next batch restages LDS
            }
        }

        // ---- softmax -> ps; zbar; single V matvec ----
        if (tid < 128 && c > 0) {
            int hd = tid >> 5, e = tid & 31;
            float m = -INFINITY;
            for (int i = 0; i < c; ++i) m = fmaxf(m, scl[i * 4 + hd]);
            float l = 0.f;
            for (int i = 0; i < c; ++i) l += __expf(scl[i * 4 + hd] - m);
            if (e < c) ps[e * 4 + hd] = __expf(scl[e * 4 + hd] - m) / l;
        }
        __syncthreads();
        {   // zbar[h] = sum_e p[h][e] * z_e   (coalesced LDS reads)
            int i = tid & 127, hb = tid >> 7;
#pragma unroll
            for (int s = 0; s < 2; ++s) {
                int h = hb * 2 + s;
                float a = 0.f;
                for (int e = 0; e < c; ++e)
                    a = fmaf(ps[e * 4 + h], zs[(size_t)e * 128 + i], a);
                zbl[h * 128 + i] = a;
            }
        }
        __syncthreads();
        // sv = Wv . zbar(head-of-output) + bv  (one 1-item matvec)
        pb[g * 32 + jj] = mv_ks1_g8(WT_v, zbl + (jj >> 3) * 128, g, jj);
        __syncthreads();
        if (g == 0) {
            float4 vv = add4(comb1_g8(pb, jj), *(const float4*)(bv + jj * 4));
            if (c == 0) vv = F4Z;
            *(float4*)(sv + jj * 4) = vv;
        }
        __syncthreads();
        pb[g * 32 + jj] = mv_ks1_g8(WT_ao, sv, g, jj);
        __syncthreads();
        if (g == 0) {
            float4 z4;
            if (c > 0) z4 = add4(comb1_g8(pb, jj), *(const float4*)(aob + jj * 4));
            else z4 = *(const float4*)(tfv + jj * 4);
            *(float4*)(xu + jj * 4) = z4;  // reuse xu as z
        }
        __syncthreads();
        pb[g * 32 + jj] = mv_ks1_g8(WT_op, xu, g, jj);
        __syncthreads();
        if (layer == 0) {
            if (g == 0) {
                float4 a = relu4(add4(comb1_g8(pb, jj), *(const float4*)(opb + jj * 4)));
                *(float4*)(P.x + (size_t)u * 128 + jj * 4) = a;
            }
        } else {
            // layer 1: emb head
            if (g == 0)
                *(float4*)(x0u + jj * 4) =
                    relu4(add4(comb1_g8(pb, jj), *(const float4*)(opb + jj * 4)));
            __syncthreads();
            pb[g * 32 + jj] = mv_ks1_g8(P.WT + 15 * MSTRIDE, x0u, g, jj);
            __syncthreads();
            if (g == 0)
                *(float4*)(tfv + jj * 4) =
                    relu4(add4(comb1_g8(pb, jj), *(const float4*)(P.o1b + jj * 4)));
            __syncthreads();
            pb[g * 32 + jj] = mv_ks1_g8_64(P.WT + 17 * MSTRIDE, tfv, g, jj);
            __syncthreads();
            if (g == 0 && jj < 16)
                *(float4*)(P.emb + (size_t)b * 64 + jj * 4) =
                    add4(comb1_g8(pb, jj), *(const float4*)(P.o2b + jj * 4));
        }
        // last barrier: blocks that don't run the pair head arrive-only
        gbar(P.bar, NBLK * (2 + layer), layer == 0 || b < N_PAIRS);
    }

    // ================= pair head (blocks 0..127) =================
    if (b < N_PAIRS) {
        const float* WT_l1 = P.WT + 16 * MSTRIDE;
        const float* WT_l2 = P.WT + 18 * MSTRIDE;
        if (tid < 128)
            xu[tid] = (tid < 64) ? P.emb[(size_t)(2 * b) * 64 + tid]
                                 : P.emb[(size_t)(2 * b + 1) * 64 + (tid - 64)];
        __syncthreads();
        if (tid < 128) pb[g * 32 + jj] = mv_ks1(WT_l1, xu, g, jj);
        __syncthreads();
        if (tid < 128 && g == 0)
            *(float4*)(tfv + jj * 4) =
                relu4(add4(comb1(pb, jj), *(const float4*)(P.l1b + jj * 4)));
        __syncthreads();
        if (tid < 128) pb[g * 32 + jj] = mv_ks1_64(WT_l2, tfv, g, jj);
        __syncthreads();
        if (tid < 128 && g == 0 && jj < 16)
            *(float4*)(qv + jj * 4) =
                relu4(add4(comb1(pb, jj), *(const float4*)(P.l2b + jj * 4)));
        __syncthreads();
        if (tid < 64) {
            float v = qv[tid] * P.l3W[tid];
            v += __shfl_xor(v, 1);
            v += __shfl_xor(v, 2);
            v += __shfl_xor(v, 4);
            v += __shfl_xor(v, 8);
            v += __shfl_xor(v, 16);
            v += __shfl_xor(v, 32);
            if (tid == 0) P.out[b] = 1.f / (1.f + __expf(-(v + P.l3b[0])));
        }
    }
}

// ---------- launch ----------
extern "C" void kernel_launch(void* const* d_in, const int* in_sizes, int n_in,
                              void* d_out, int out_size, void* d_ws, size_t ws_size,
                              hipStream_t stream) {
    Params P;
    P.nf  = (const float*)d_in[0];
    P.ei  = (const int*)d_in[1];
    P.ts  = (const float*)d_in[2];
    P.tp  = (const int*)d_in[3];
    P.inW = (const float*)d_in[4];
    P.inb = (const float*)d_in[5];
    P.teW1 = (const float*)d_in[6];
    P.teb1 = (const float*)d_in[7];
    P.teW2 = (const float*)d_in[8];
    P.teb2 = (const float*)d_in[9];
    P.aiW = (const float*)d_in[10];
    P.aib = (const float*)d_in[11];
    P.aoW = (const float*)d_in[12];
    P.aob = (const float*)d_in[13];
    P.ftW = (const float*)d_in[14];
    P.ftb = (const float*)d_in[15];
    P.opW = (const float*)d_in[16];
    P.opb = (const float*)d_in[17];
    P.o1W = (const float*)d_in[18];
    P.o1b = (const float*)d_in[19];
    P.o2W = (const float*)d_in[20];
    P.o2b = (const float*)d_in[21];
    P.l1W = (const float*)d_in[22];
    P.l1b = (const float*)d_in[23];
    P.l2W = (const float*)d_in[24];
    P.l2b = (const float*)d_in[25];
    P.l3W = (const float*)d_in[26];
    P.l3b = (const float*)d_in[27];
    P.out = (float*)d_out;

    char* ws = (char*)d_ws;
    size_t off = 0;
    P.x    = (float*)(ws + off); off += (size_t)N_NODES * 128 * 4;   // 10.24 MB
    P.cnt  = (int*)  (ws + off); off += N_SLOTS * 4;
    P.lst  = (int2*) (ws + off); off += (size_t)N_SLOTS * CAP * 8;
    P.emb  = (float*)(ws + off); off += N_SLOTS * 64 * 4;
    P.WT   = (float*)(ws + off); off += (size_t)NMAT * MSTRIDE * 4;  // 1.2 MB
    P.bar  = (unsigned*)(ws + off); off += 256;                      // grid barrier

    hipMemsetAsync(P.cnt, 0, N_SLOTS * 4, stream);  // scan uses global counters
    hipMemsetAsync(P.bar, 0, 4, stream);
    k_fused<<<NBLK, 256, 0, stream>>>(P);
}